// Round 1
// baseline (3817.666 us; speedup 1.0000x reference)
//
#include <hip/hip_runtime.h>

// ---------------------------------------------------------------------------
// GraphCast-style GNN on MI355X (gfx950).
// Everything recomputed per call (graph-capture safe, stream-only ops).
// Workspace requirement ~228 MB.
// ---------------------------------------------------------------------------

typedef __attribute__((ext_vector_type(8))) short bf16x8;
typedef __attribute__((ext_vector_type(4))) float f32x4;
typedef unsigned short u16;

#define NNODES 32768
#define NEDGES 196608

#define MFMA16(a, b, c) __builtin_amdgcn_mfma_f32_16x16x32_bf16((a), (b), (c), 0, 0, 0)

__device__ __forceinline__ u16 f2bf(float f) {
    unsigned u = __float_as_uint(f);
    unsigned r = (u + 0x7FFFu + ((u >> 16) & 1u)) >> 16;  // RNE
    return (u16)r;
}
__device__ __forceinline__ float bf2f(u16 b) {
    return __uint_as_float(((unsigned)b) << 16);
}

// ---------------------------------------------------------------------------
// Weight transpose + pad + bf16 cast:  W (batch, K, Nout) fp32 -> WT (batch, NP, Kpad) bf16
// Tiled through LDS for coalescing. Kpad multiple of 32; zero-fill pads.
// ---------------------------------------------------------------------------
__global__ void wtrans_kernel(const float* __restrict__ W, u16* __restrict__ WT,
                              int K, int Nout, int Kpad, int NP) {
    __shared__ u16 tile[32][33];
    const int b = blockIdx.z;
    const int k0 = blockIdx.x * 32, n0 = blockIdx.y * 32;
    const int tx = threadIdx.x & 31, ty = threadIdx.x >> 5;  // 32 x 8
    #pragma unroll
    for (int i = 0; i < 4; i++) {
        int k = k0 + ty + 8 * i, n = n0 + tx;
        float v = (k < K && n < Nout) ? W[((size_t)b * K + k) * Nout + n] : 0.f;
        tile[ty + 8 * i][tx] = f2bf(v);
    }
    __syncthreads();
    #pragma unroll
    for (int i = 0; i < 4; i++) {
        int n = n0 + ty + 8 * i, k = k0 + tx;
        if (n < NP && k < Kpad) WT[((size_t)b * NP + n) * Kpad + k] = tile[tx][ty + 8 * i];
    }
}

// ---------------------------------------------------------------------------
// edge_index normalization: reference dtype is int64 but harness contract says
// int32. Detect which payload we actually got (int64 little-endian => odd words
// all zero) and emit flat int32 [src(E) | dst(E)].
// ---------------------------------------------------------------------------
__global__ void idx_norm_kernel(const int* __restrict__ raw, int* __restrict__ sd) {
    __shared__ int nz;
    if (threadIdx.x == 0) nz = 0;
    __syncthreads();
    for (int i = threadIdx.x; i < 512; i += 256)
        if (raw[2 * i + 1] != 0) atomicAdd(&nz, 1);
    __syncthreads();
    const bool is64 = (nz == 0);
    int idx = blockIdx.x * 256 + threadIdx.x;
    if (idx < 2 * NEDGES) sd[idx] = is64 ? raw[2 * idx] : raw[idx];
}

// ---------------------------------------------------------------------------
// CSR build (by dst), reused across all 8 layers.
// ---------------------------------------------------------------------------
__global__ void csr_count_kernel(const int* __restrict__ dsti, int* __restrict__ deg) {
    int e = blockIdx.x * 256 + threadIdx.x;
    atomicAdd(&deg[dsti[e]], 1);
}

__global__ void csr_scan_kernel(const int* __restrict__ deg, int* __restrict__ off,
                                int* __restrict__ cur) {
    __shared__ int part[1024];
    const int t = threadIdx.x;
    int local[32];
    int s = 0;
    #pragma unroll
    for (int i = 0; i < 32; i++) { local[i] = deg[t * 32 + i]; s += local[i]; }
    part[t] = s;
    __syncthreads();
    for (int d = 1; d < 1024; d <<= 1) {
        int v = (t >= d) ? part[t - d] : 0;
        __syncthreads();
        part[t] += v;
        __syncthreads();
    }
    int excl = (t == 0) ? 0 : part[t - 1];
    #pragma unroll
    for (int i = 0; i < 32; i++) {
        off[t * 32 + i] = excl;
        cur[t * 32 + i] = excl;
        excl += local[i];
    }
    if (t == 1023) off[NNODES] = excl;
}

__global__ void csr_fill_kernel(const int* __restrict__ dsti, int* __restrict__ cur,
                                int* __restrict__ perm) {
    int e = blockIdx.x * 256 + threadIdx.x;
    int pos = atomicAdd(&cur[dsti[e]], 1);
    perm[pos] = e;
}

// agg[n][c] = sum over edges with dst==n of edge_b[e][c]  (bf16 in, fp32 out)
__global__ void gather_kernel(const u16* __restrict__ edge_b, const int* __restrict__ perm,
                              const int* __restrict__ off, float* __restrict__ agg) {
    int idx = blockIdx.x * 256 + threadIdx.x;  // N*128 threads
    int n = idx >> 7, c = idx & 127;
    int a = off[n], b = off[n + 1];
    float s = 0.f;
    for (int i = a; i < b; i++) s += bf2f(edge_b[(size_t)perm[i] * 128 + c]);
    agg[idx] = s;
}

// ---------------------------------------------------------------------------
// Fused 2-layer MLP (Linear -> SiLU -> Linear [-> +resid -> LayerNorm]).
// Block = 256 threads (4 waves) = 64 rows. Wave computes 64 x (NH/4) of GEMM1
// (4 M-frags x NT1 N-frags), h -> LDS bf16 in two K-halves, then each wave
// computes its 16 rows x NOUT of GEMM2.
//
// IN modes:  0 = edge (gather node[src]|node[dst]|edge_bf)
//            1 = node (node_bf | agg fp32->bf16)
//            2 = direct bf16 matrix, row stride A1S
//            3 = raw_edge_feat (3 -> padded 32)
// OUT modes: 0 = +b2 +resid, LayerNorm(g,bt), store fp32+bf16
//            1 = +b2, store fp32+bf16
//            2 = decoder: +b2, store transposed fp32 to d_out, cols < 69
// ---------------------------------------------------------------------------
struct MlpP {
    const u16* A1;
    const u16* A1b;
    const float* Araw;
    const int* src;
    const int* dsti;
    const u16* W1T;   // [NH][K1] bf16
    const u16* W2T;   // [NOUT][NH] bf16
    const float* b1;
    const float* b2;
    const float* g;
    const float* bt;
    const float* resid;
    float* outF;
    u16* outB;
    float* outDec;
};

template <int K1, int NH, int NOUT, int IN, int OUT, int A1S>
__global__ __launch_bounds__(256, 2) void mlp_kernel(MlpP p) {
    static_assert(K1 % 32 == 0 && NH % 64 == 0 && NOUT % 16 == 0, "dims");
    constexpr int NT1 = NH / 64;            // N-frags per wave, GEMM1
    constexpr int NT2 = NOUT / 16;          // N-frags per wave, GEMM2
    constexpr int SH2 = NH / 2 + 8;         // padded LDS stride for h half
    constexpr int OFF_SB = 4096;
    constexpr int OFF_IDX = 4096 + NH * 64;
    constexpr int OFF_SW2 = 64 * SH2 * 2;
    constexpr int SMEM_A = OFF_IDX + 512;
    constexpr int SMEM_B = OFF_SW2 + NOUT * 64;
    constexpr int SMEM = (SMEM_A > SMEM_B) ? SMEM_A : SMEM_B;

    __shared__ __align__(16) char smem[SMEM];
    u16* sA = (u16*)smem;                    // [64][32] phase 1
    u16* sB = (u16*)(smem + OFF_SB);         // [NH][32] phase 1
    int* sIdx = (int*)(smem + OFF_IDX);      // [128]    phase 1 (IN==0)
    u16* sH = (u16*)smem;                    // [64][SH2] phase 2
    u16* sW2 = (u16*)(smem + OFF_SW2);       // [NOUT][32] phase 2

    const int tid = threadIdx.x;
    const int wave = tid >> 6, lane = tid & 63;
    const int lhi = lane >> 4, llo = lane & 15;
    const int r0 = blockIdx.x * 64;

    if constexpr (IN == 0) {
        if (tid < 64) {
            sIdx[tid] = p.src[r0 + tid];
            sIdx[64 + tid] = p.dsti[r0 + tid];
        }
        __syncthreads();
    }

    const f32x4 fz = {0.f, 0.f, 0.f, 0.f};
    f32x4 acc[4][NT1];
    #pragma unroll
    for (int m = 0; m < 4; m++)
        #pragma unroll
        for (int j = 0; j < NT1; j++) acc[m][j] = fz;

    const int arow = tid >> 2, acg = tid & 3;

    // ---------------- GEMM1: [64 x K1] @ [K1 x NH] ----------------
    for (int kb = 0; kb < K1; kb += 32) {
        {   // stage A tile [64][32]
            const int k0 = kb + acg * 8;
            u16* dA = sA + arow * 32 + acg * 8;
            if constexpr (IN == 0) {
                uint4 v;
                if (k0 < 256)
                    v = *(const uint4*)(p.A1 + (size_t)sIdx[arow] * 256 + k0);
                else if (k0 < 512)
                    v = *(const uint4*)(p.A1 + (size_t)sIdx[64 + arow] * 256 + (k0 - 256));
                else
                    v = *(const uint4*)(p.A1b + (size_t)(r0 + arow) * 128 + (k0 - 512));
                *(uint4*)dA = v;
            } else if constexpr (IN == 1) {
                if (k0 < 256) {
                    *(uint4*)dA = *(const uint4*)(p.A1 + (size_t)(r0 + arow) * 256 + k0);
                } else {
                    const float* q = p.Araw + (size_t)(r0 + arow) * 128 + (k0 - 256);
                    #pragma unroll
                    for (int i = 0; i < 8; i++) dA[i] = f2bf(q[i]);
                }
            } else if constexpr (IN == 2) {
                *(uint4*)dA = *(const uint4*)(p.A1 + (size_t)(r0 + arow) * A1S + k0);
            } else {  // IN == 3 : raw edge feats (3 -> 32 padded)
                u16 v[8] = {0, 0, 0, 0, 0, 0, 0, 0};
                if (acg == 0) {
                    const float* q = p.Araw + (size_t)(r0 + arow) * 3;
                    v[0] = f2bf(q[0]); v[1] = f2bf(q[1]); v[2] = f2bf(q[2]);
                }
                #pragma unroll
                for (int i = 0; i < 8; i++) dA[i] = v[i];
            }
        }
        // stage B tile [NH][32] from W1T
        #pragma unroll
        for (int j = 0; j < NH / 64; j++) {
            int c = tid + 256 * j;
            int n = c >> 2, cg = c & 3;
            *(uint4*)(sB + n * 32 + cg * 8) =
                *(const uint4*)(p.W1T + (size_t)n * K1 + kb + cg * 8);
        }
        __syncthreads();
        bf16x8 a[4];
        #pragma unroll
        for (int m = 0; m < 4; m++)
            a[m] = *(const bf16x8*)(sA + (m * 16 + llo) * 32 + lhi * 8);
        #pragma unroll
        for (int j = 0; j < NT1; j++) {
            bf16x8 b = *(const bf16x8*)(sB + (wave * (NH / 4) + j * 16 + llo) * 32 + lhi * 8);
            #pragma unroll
            for (int m = 0; m < 4; m++) acc[m][j] = MFMA16(a[m], b, acc[m][j]);
        }
        __syncthreads();
    }

    // ---------------- phase 2: h -> LDS (bf16, two K-halves), GEMM2 ----------------
    f32x4 acc2[NT2];
    #pragma unroll
    for (int j = 0; j < NT2; j++) acc2[j] = fz;

    #pragma unroll
    for (int half = 0; half < 2; half++) {
        if ((wave >> 1) == half) {  // waves owning these NH/2 hidden cols write h
            #pragma unroll
            for (int j = 0; j < NT1; j++) {
                int colg = wave * (NH / 4) + j * 16 + llo;
                int coll = colg - half * (NH / 2);
                float bias = p.b1[colg];
                #pragma unroll
                for (int m = 0; m < 4; m++)
                    #pragma unroll
                    for (int r = 0; r < 4; r++) {
                        int row = m * 16 + lhi * 4 + r;
                        float v = acc[m][j][r] + bias;
                        sH[row * SH2 + coll] = f2bf(v / (1.f + __expf(-v)));  // SiLU
                    }
            }
        }
        __syncthreads();
        for (int kb2 = 0; kb2 < NH / 2; kb2 += 32) {
            #pragma unroll
            for (int j = 0; j < (NOUT * 4 + 255) / 256; j++) {
                int c = tid + 256 * j;
                if (c < NOUT * 4) {
                    int n = c >> 2, cg = c & 3;
                    *(uint4*)(sW2 + n * 32 + cg * 8) =
                        *(const uint4*)(p.W2T + (size_t)n * NH + half * (NH / 2) + kb2 + cg * 8);
                }
            }
            __syncthreads();
            bf16x8 a2 = *(const bf16x8*)(sH + (wave * 16 + llo) * SH2 + kb2 + lhi * 8);
            #pragma unroll
            for (int j = 0; j < NT2; j++) {
                bf16x8 b = *(const bf16x8*)(sW2 + (j * 16 + llo) * 32 + lhi * 8);
                acc2[j] = MFMA16(a2, b, acc2[j]);
            }
            __syncthreads();
        }
    }

    // ---------------- epilogue ----------------
    if constexpr (OUT == 0) {  // +bias +resid, LayerNorm
        float s1[4] = {0, 0, 0, 0}, s2[4] = {0, 0, 0, 0};
        #pragma unroll
        for (int j = 0; j < NT2; j++) {
            int col = j * 16 + llo;
            float bias = p.b2[col];
            #pragma unroll
            for (int r = 0; r < 4; r++) {
                int row = wave * 16 + lhi * 4 + r;
                float v = acc2[j][r] + bias + p.resid[(size_t)(r0 + row) * NOUT + col];
                acc2[j][r] = v;
                s1[r] += v;
                s2[r] += v * v;
            }
        }
        #pragma unroll
        for (int mm = 1; mm < 16; mm <<= 1) {
            #pragma unroll
            for (int r = 0; r < 4; r++) {
                s1[r] += __shfl_xor(s1[r], mm, 64);
                s2[r] += __shfl_xor(s2[r], mm, 64);
            }
        }
        #pragma unroll
        for (int r = 0; r < 4; r++) {
            float mean = s1[r] * (1.f / NOUT);
            float var = s2[r] * (1.f / NOUT) - mean * mean;
            s1[r] = mean;
            s2[r] = rsqrtf(var + 1e-5f);
        }
        #pragma unroll
        for (int j = 0; j < NT2; j++) {
            int col = j * 16 + llo;
            float gg = p.g[col], bb = p.bt[col];
            #pragma unroll
            for (int r = 0; r < 4; r++) {
                int row = wave * 16 + lhi * 4 + r;
                float v = (acc2[j][r] - s1[r]) * s2[r] * gg + bb;
                size_t o = (size_t)(r0 + row) * NOUT + col;
                p.outF[o] = v;
                p.outB[o] = f2bf(v);
            }
        }
    } else if constexpr (OUT == 1) {  // plain +bias
        #pragma unroll
        for (int j = 0; j < NT2; j++) {
            int col = j * 16 + llo;
            float bias = p.b2[col];
            #pragma unroll
            for (int r = 0; r < 4; r++) {
                int row = wave * 16 + lhi * 4 + r;
                float v = acc2[j][r] + bias;
                size_t o = (size_t)(r0 + row) * NOUT + col;
                p.outF[o] = v;
                p.outB[o] = f2bf(v);
            }
        }
    } else {  // decoder: transposed store, real cols < 69
        #pragma unroll
        for (int j = 0; j < NT2; j++) {
            int col = j * 16 + llo;
            if (col < 69) {
                float bias = p.b2[col];
                #pragma unroll
                for (int r = 0; r < 4; r++) {
                    int row = wave * 16 + lhi * 4 + r;
                    p.outDec[(size_t)col * NNODES + (r0 + row)] = acc2[j][r] + bias;
                }
            }
        }
    }
}

// ---------------------------------------------------------------------------
extern "C" void kernel_launch(void* const* d_in, const int* in_sizes, int n_in,
                              void* d_out, int out_size, void* d_ws, size_t ws_size,
                              hipStream_t stream) {
    (void)in_sizes; (void)n_in; (void)out_size; (void)ws_size;

    const float* x       = (const float*)d_in[0];
    const int*   eidx    = (const int*)d_in[1];
    const float* raw_e   = (const float*)d_in[2];
    const float* enc_w1  = (const float*)d_in[3];
    const float* enc_b1  = (const float*)d_in[4];
    const float* enc_w2  = (const float*)d_in[5];
    const float* enc_b2  = (const float*)d_in[6];
    const float* eenc_w1 = (const float*)d_in[7];
    const float* eenc_b1 = (const float*)d_in[8];
    const float* eenc_w2 = (const float*)d_in[9];
    const float* eenc_b2 = (const float*)d_in[10];
    const float* pe_w1   = (const float*)d_in[11];
    const float* pe_b1   = (const float*)d_in[12];
    const float* pe_w2   = (const float*)d_in[13];
    const float* pe_b2   = (const float*)d_in[14];
    const float* pe_g    = (const float*)d_in[15];
    const float* pe_bt   = (const float*)d_in[16];
    const float* pn_w1   = (const float*)d_in[17];
    const float* pn_b1   = (const float*)d_in[18];
    const float* pn_w2   = (const float*)d_in[19];
    const float* pn_b2   = (const float*)d_in[20];
    const float* pn_g    = (const float*)d_in[21];
    const float* pn_bt   = (const float*)d_in[22];
    const float* dec_w1  = (const float*)d_in[23];
    const float* dec_b1  = (const float*)d_in[24];
    const float* dec_w2  = (const float*)d_in[25];
    const float* dec_b2  = (const float*)d_in[26];

    // ---- workspace carve (~228 MB) ----
    char* ws = (char*)d_ws;
    size_t o = 0;
    auto alloc = [&](size_t bytes) -> void* {
        void* p = ws + o;
        o += (bytes + 255) & ~(size_t)255;
        return p;
    };
    float* node_f = (float*)alloc((size_t)NNODES * 256 * 4);
    u16*   node_b = (u16*)  alloc((size_t)NNODES * 256 * 2);
    float* edge_f = (float*)alloc((size_t)NEDGES * 128 * 4);
    u16*   edge_b = (u16*)  alloc((size_t)NEDGES * 128 * 2);
    float* agg    = (float*)alloc((size_t)NNODES * 128 * 4);
    u16*   xT     = (u16*)  alloc((size_t)NNODES * 96 * 2);
    u16*   encw1  = (u16*)  alloc(256 * 96 * 2);
    u16*   encw2  = (u16*)  alloc(256 * 256 * 2);
    u16*   eencw1 = (u16*)  alloc(128 * 32 * 2);
    u16*   eencw2 = (u16*)  alloc(128 * 128 * 2);
    u16*   pew1   = (u16*)  alloc((size_t)8 * 512 * 640 * 2);
    u16*   pew2   = (u16*)  alloc((size_t)8 * 128 * 512 * 2);
    u16*   pnw1   = (u16*)  alloc((size_t)8 * 512 * 384 * 2);
    u16*   pnw2   = (u16*)  alloc((size_t)8 * 256 * 512 * 2);
    u16*   decw1  = (u16*)  alloc(256 * 256 * 2);
    u16*   decw2  = (u16*)  alloc(80 * 256 * 2);
    int*   sd     = (int*)  alloc((size_t)2 * NEDGES * 4);
    int*   deg    = (int*)  alloc((size_t)NNODES * 4);
    int*   off_   = (int*)  alloc((size_t)(NNODES + 1) * 4);
    int*   cur    = (int*)  alloc((size_t)NNODES * 4);
    int*   perm   = (int*)  alloc((size_t)NEDGES * 4);

    // ---- weight prep (transpose + pad + bf16) ----
    auto WT = [&](const float* W, u16* dst, int K, int Nout, int Kpad, int NP, int batch) {
        dim3 g(Kpad / 32, (NP + 31) / 32, batch);
        wtrans_kernel<<<g, 256, 0, stream>>>(W, dst, K, Nout, Kpad, NP);
    };
    WT(x,       xT,     70, NNODES, 96, NNODES, 1);   // x (70,N) -> xT (N,96)
    WT(enc_w1,  encw1,  70, 256,  96,  256, 1);
    WT(enc_w2,  encw2,  256, 256, 256, 256, 1);
    WT(eenc_w1, eencw1, 3, 128,   32,  128, 1);
    WT(eenc_w2, eencw2, 128, 128, 128, 128, 1);
    WT(pe_w1,   pew1,   640, 512, 640, 512, 8);
    WT(pe_w2,   pew2,   512, 128, 512, 128, 8);
    WT(pn_w1,   pnw1,   384, 512, 384, 512, 8);
    WT(pn_w2,   pnw2,   512, 256, 512, 256, 8);
    WT(dec_w1,  decw1,  256, 256, 256, 256, 1);
    WT(dec_w2,  decw2,  256, 69,  256, 80, 1);

    // ---- indices + CSR ----
    idx_norm_kernel<<<1536, 256, 0, stream>>>(eidx, sd);
    hipMemsetAsync(deg, 0, (size_t)NNODES * 4, stream);
    csr_count_kernel<<<NEDGES / 256, 256, 0, stream>>>(sd + NEDGES, deg);
    csr_scan_kernel<<<1, 1024, 0, stream>>>(deg, off_, cur);
    csr_fill_kernel<<<NEDGES / 256, 256, 0, stream>>>(sd + NEDGES, cur, perm);

    // ---- encoders ----
    {
        MlpP p{};
        p.A1 = xT; p.W1T = encw1; p.W2T = encw2; p.b1 = enc_b1; p.b2 = enc_b2;
        p.outF = node_f; p.outB = node_b;
        mlp_kernel<96, 256, 256, 2, 1, 96><<<NNODES / 64, 256, 0, stream>>>(p);
    }
    {
        MlpP p{};
        p.Araw = raw_e; p.W1T = eencw1; p.W2T = eencw2; p.b1 = eenc_b1; p.b2 = eenc_b2;
        p.outF = edge_f; p.outB = edge_b;
        mlp_kernel<32, 128, 128, 3, 1, 0><<<NEDGES / 64, 256, 0, stream>>>(p);
    }

    // ---- processor layers ----
    for (int l = 0; l < 8; l++) {
        {
            MlpP p{};
            p.A1 = node_b; p.A1b = edge_b; p.src = sd; p.dsti = sd + NEDGES;
            p.W1T = pew1 + (size_t)l * 512 * 640;
            p.W2T = pew2 + (size_t)l * 128 * 512;
            p.b1 = pe_b1 + l * 512; p.b2 = pe_b2 + l * 128;
            p.g = pe_g + l * 128; p.bt = pe_bt + l * 128;
            p.resid = edge_f; p.outF = edge_f; p.outB = edge_b;
            mlp_kernel<640, 512, 128, 0, 0, 0><<<NEDGES / 64, 256, 0, stream>>>(p);
        }
        gather_kernel<<<NNODES * 128 / 256, 256, 0, stream>>>(edge_b, perm, off_, agg);
        {
            MlpP p{};
            p.A1 = node_b; p.Araw = agg;
            p.W1T = pnw1 + (size_t)l * 512 * 384;
            p.W2T = pnw2 + (size_t)l * 256 * 512;
            p.b1 = pn_b1 + l * 512; p.b2 = pn_b2 + l * 256;
            p.g = pn_g + l * 256; p.bt = pn_bt + l * 256;
            p.resid = node_f; p.outF = node_f; p.outB = node_b;
            mlp_kernel<384, 512, 256, 1, 0, 0><<<NNODES / 64, 256, 0, stream>>>(p);
        }
    }

    // ---- decoder ----
    {
        MlpP p{};
        p.A1 = node_b; p.W1T = decw1; p.W2T = decw2; p.b1 = dec_b1; p.b2 = dec_b2;
        p.outDec = (float*)d_out;
        mlp_kernel<256, 256, 80, 2, 2, 256><<<NNODES / 64, 256, 0, stream>>>(p);
    }
}